// Round 8
// baseline (66.440 us; speedup 1.0000x reference)
//
#include <hip/hip_runtime.h>
#include <math.h>

typedef unsigned short u16;
typedef unsigned int   u32;
typedef unsigned long long u64;

#define Bb   2
#define Cc   19
#define Hh   128
#define Ww   128
#define CHc  64
#define HWs  16384
#define NPIX 32768
#define EPSf 1e-8f
#define FSTR 64               // feature vector: exactly 128 B, line-aligned
#define PSTR 32               // prob vector: 64 B (19 real, pad 0)
#define WROW 129              // padded row stride in pixels (kills power-of-2 L1 aliasing)
#define BPIX (Hh*WROW)        // 16512 padded pixels per batch image

typedef _Float16 h2 __attribute__((ext_vector_type(2)));

__device__ inline float fd(u32 a, u32 b, float c) {
  h2 ha = __builtin_bit_cast(h2, a);
  h2 hb = __builtin_bit_cast(h2, b);
#if __has_builtin(__builtin_amdgcn_fdot2)
  return __builtin_amdgcn_fdot2(ha, hb, c, false);
#else
  return c + (float)ha[0] * (float)hb[0] + (float)ha[1] * (float)hb[1];
#endif
}

__device__ inline u32 pk(float a, float b) {
  h2 h; h[0] = (_Float16)a; h[1] = (_Float16)b;
  return __builtin_bit_cast(u32, h);
}

// ---------- PRE: feat normalize+transpose (blocks 0..1023) | softmax (1024..1151) ----------
__global__ __launch_bounds__(256) void pre_kernel(
    const float* __restrict__ logits,
    const float* __restrict__ xsrc, const float* __restrict__ xema,
    u16* __restrict__ osrc, u16* __restrict__ oema, u16* __restrict__ pt) {
  __shared__ float smem[5376];
  int bid = blockIdx.x;
  int t = threadIdx.x;

  if (bid < 1024) {
    float* tile = smem;                 // 64*65
    float* part = smem + 4160;          // 256
    float* invn = smem + 4416;          // 64
    int xb = bid & 255, b = (bid >> 8) & 1, z = bid >> 9;
    const float* in = z ? xema : xsrc;
    u16* out = z ? oema : osrc;
    int pix0 = xb * 64;                 // 64 consecutive pixels, all in row h
    int h = xb >> 1, w0 = (xb & 1) * 64;
    int w = t >> 6, l = t & 63;

    const float* src = in + (size_t)b * CHc * HWs + pix0;
#pragma unroll
    for (int cc = 0; cc < 16; cc++) {
      int c = cc * 4 + w;
      tile[c * 65 + l] = src[(size_t)c * HWs + l];
    }
    __syncthreads();
    float s = 0.f;
#pragma unroll
    for (int c = w * 16; c < w * 16 + 16; c++) { float a = tile[c * 65 + l]; s += a * a; }
    part[w * 64 + l] = s;
    __syncthreads();
    if (t < 64) {
      float n = part[t] + part[64 + t] + part[128 + t] + part[192 + t];
      invn[t] = 1.0f / fmaxf(sqrtf(n), EPSf);
    }
    __syncthreads();
    // 64 px * 8 uint4 (64 halves) per block, padded-row layout
    size_t vbase = (size_t)b * BPIX + (size_t)h * WROW + w0;
#pragma unroll
    for (int i = t; i < 512; i += 256) {
      int px = i >> 3, q = i & 7;
      float iv = invn[px];
      float v[8];
#pragma unroll
      for (int k = 0; k < 8; k++) v[k] = tile[(q * 8 + k) * 65 + px] * iv;
      uint4 u = make_uint4(pk(v[0], v[1]), pk(v[2], v[3]), pk(v[4], v[5]), pk(v[6], v[7]));
      *((uint4*)(out + (vbase + px) * FSTR) + q) = u;
    }
  } else {
    float* lp = smem;                   // 256*21
    int pb = bid - 1024;
    int gpix = pb * 256 + t;
    int b = gpix >> 14, hw = gpix & (HWs - 1);
    const float* lg = logits + (size_t)b * Cc * HWs + hw;
    float v[Cc]; float m = -INFINITY;
#pragma unroll
    for (int c = 0; c < Cc; c++) { v[c] = lg[(size_t)c * HWs]; m = fmaxf(m, v[c]); }
    float s = 0.f;
#pragma unroll
    for (int c = 0; c < Cc; c++) { v[c] = expf(v[c] - m); s += v[c]; }
    float inv = 1.0f / s;
#pragma unroll
    for (int c = 0; c < Cc; c++) lp[t * 21 + c] = v[c] * inv;
    __syncthreads();
#pragma unroll
    for (int i = t; i < 1024; i += 256) {
      int px = i >> 2, q = i & 3;
      int gp = pb * 256 + px;
      int bb2 = gp >> 14, hw2 = gp & (HWs - 1);
      int h2i = hw2 >> 7, w2i = hw2 & 127;
      size_t pidx = (size_t)bb2 * BPIX + (size_t)h2i * WROW + w2i;
      float v8[8];
#pragma unroll
      for (int k = 0; k < 8; k++) {
        int c = q * 8 + k;
        v8[k] = (c < Cc) ? lp[px * 21 + c] : 0.f;
      }
      uint4 u = make_uint4(pk(v8[0], v8[1]), pk(v8[2], v8[3]), pk(v8[4], v8[5]), pk(v8[6], v8[7]));
      *((uint4*)(pt + pidx * PSTR) + q) = u;
    }
  }
}

// ---------- ST: fused src-sim + trg rank-select, ONE pixel per wave ----------
__global__ __launch_bounds__(256, 4) void st_kernel(
    const u16* __restrict__ fsrc, const u16* __restrict__ fema,
    const u16* __restrict__ pt, const int* __restrict__ gt,
    const float* __restrict__ mix, float* __restrict__ partials) {
  __shared__ u32 ksh[4][64];
  __shared__ float sacc[4][8];
  int bid = blockIdx.x;
  int swz = ((bid & 7) << 10) | (bid >> 3);        // 8192 % 8 == 0: bijective
  int t = threadIdx.x, wv = t >> 6, lane = t & 63;
  int pix = __builtin_amdgcn_readfirstlane((swz << 2) | wv);
  int b = pix >> 14, hw = pix & (HWs - 1);
  int h = hw >> 7, w = hw & 127;
  int dh = lane / 7 - 3, dw = lane % 7 - 3;
  bool lact = lane < 49;
  int hn = h + dh, wn = w + dw;
  bool inb = lact && ((unsigned)hn < 128u) && ((unsigned)wn < 128u);
  int lin_hwn = inb ? ((hn << 7) | wn) : hw;        // original-layout neighbor (for gt)
  size_t bb = (size_t)b << 14;                      // original-layout batch base
  size_t bpad = (size_t)b * BPIX;                   // padded-layout batch base
  size_t cidx = bpad + (size_t)h * WROW + w;        // padded center
  size_t nidx = inb ? (bpad + (size_t)hn * WROW + wn) : cidx;  // padded neighbor

  // scalar branch conditions (uniform loads -> SGPR)
  int gtc = __builtin_amdgcn_readfirstlane(gt[bb + hw]);
  u32 mixu = __builtin_amdgcn_readfirstlane(__float_as_uint(mix[bb + hw]));
  bool do_t = __uint_as_float(mixu) < 0.5f;        // wave-uniform

  const uint4* sc = (const uint4*)(fsrc + cidx * FSTR);   // uniform center
  const uint4* sn = (const uint4*)(fsrc + nidx * FSTR);   // per-lane gather (1 line each)
  const uint4* ec = (const uint4*)(fema + cidx * FSTR);
  const uint4* en = (const uint4*)(fema + nidx * FSTR);

  // ---- issue all neighbor gathers up front ----
  uint4 S[8], E[8];
#pragma unroll
  for (int q = 0; q < 8; q++) S[q] = sn[q];
  if (do_t) {
#pragma unroll
    for (int q = 0; q < 8; q++) E[q] = en[q];
  }

  float psum = 0, ssum = 0, posa = 0, nega = 0, pcntW = 0, vcntW = 0, cntW = 0;

  // ---- source cosine sim ----
  if (gtc != 255) {
    float d0 = 0, d1 = 0, d2 = 0, d3 = 0;
#pragma unroll
    for (int q = 0; q < 8; q += 4) {
      uint4 a0 = sc[q], a1 = sc[q+1], a2 = sc[q+2], a3 = sc[q+3];
      d0 = fd(a0.x,S[q].x,d0);   d0 = fd(a0.y,S[q].y,d0);   d0 = fd(a0.z,S[q].z,d0);   d0 = fd(a0.w,S[q].w,d0);
      d1 = fd(a1.x,S[q+1].x,d1); d1 = fd(a1.y,S[q+1].y,d1); d1 = fd(a1.z,S[q+1].z,d1); d1 = fd(a1.w,S[q+1].w,d1);
      d2 = fd(a2.x,S[q+2].x,d2); d2 = fd(a2.y,S[q+2].y,d2); d2 = fd(a2.z,S[q+2].z,d2); d2 = fd(a2.w,S[q+2].w,d2);
      d3 = fd(a3.x,S[q+3].x,d3); d3 = fd(a3.y,S[q+3].y,d3); d3 = fd(a3.z,S[q+3].z,d3); d3 = fd(a3.w,S[q+3].w,d3);
    }
    float sims = inb ? ((d0 + d1) + (d2 + d3)) : 0.f;  // zero-pad unfold -> sim 0
    int gtn = inb ? gt[bb + lin_hwn] : 0;              // zero-pad unfold -> gt 0
    bool pos = (gtn == gtc);
    if (lact) { ssum = sims; if (pos) psum = sims; }
    u64 mk = __ballot(lact && pos);
    pcntW = (float)__popcll(mk);
    vcntW = 1.f;
  }

  // ---- target branch (wave-uniform) ----
  if (do_t) {
    const uint4* pc = (const uint4*)(pt + cidx * PSTR);
    const uint4* pn = (const uint4*)(pt + nidx * PSTR);
    uint4 P0 = pn[0], P1 = pn[1], P2 = pn[2];

    float d0 = 0, d1 = 0, d2 = 0, d3 = 0;
#pragma unroll
    for (int q = 0; q < 8; q += 4) {
      uint4 a0 = ec[q], a1 = ec[q+1], a2 = ec[q+2], a3 = ec[q+3];
      d0 = fd(a0.x,E[q].x,d0);   d0 = fd(a0.y,E[q].y,d0);   d0 = fd(a0.z,E[q].z,d0);   d0 = fd(a0.w,E[q].w,d0);
      d1 = fd(a1.x,E[q+1].x,d1); d1 = fd(a1.y,E[q+1].y,d1); d1 = fd(a1.z,E[q+1].z,d1); d1 = fd(a1.w,E[q+1].w,d1);
      d2 = fd(a2.x,E[q+2].x,d2); d2 = fd(a2.y,E[q+2].y,d2); d2 = fd(a2.z,E[q+2].z,d2); d2 = fd(a2.w,E[q+2].w,d2);
      d3 = fd(a3.x,E[q+3].x,d3); d3 = fd(a3.y,E[q+3].y,d3); d3 = fd(a3.z,E[q+3].z,d3); d3 = fd(a3.w,E[q+3].w,d3);
    }
    float dote = (d0 + d1) + (d2 + d3);
    float p0 = 0, p1 = 0, p2 = 0;
    {
      uint4 a0 = pc[0], a1 = pc[1], a2 = pc[2];
      p0 = fd(a0.x,P0.x,p0); p0 = fd(a0.y,P0.y,p0); p0 = fd(a0.z,P0.z,p0); p0 = fd(a0.w,P0.w,p0);
      p1 = fd(a1.x,P1.x,p1); p1 = fd(a1.y,P1.y,p1); p1 = fd(a1.z,P1.z,p1); p1 = fd(a1.w,P1.w,p1);
      p2 = fd(a2.x,P2.x,p2); p2 = fd(a2.y,P2.y,p2); p2 = fd(a2.z,P2.z,p2); p2 = fd(a2.w,P2.w,p2);
    }
    float dotp = (p0 + p1) + p2;

    float v  = inb ? dote : 0.f;
    float cp = inb ? dotp : (1.0f / 19.f);

    // u32 sortable key: top-26 monotone float bits | lane (all 49 keys distinct)
    u32 bits = __float_as_uint(v);
    u32 mono = (bits & 0x80000000u) ? ~bits : (bits | 0x80000000u);
    u32 key = (mono & 0xFFFFFFC0u) | (u32)lane;
    ksh[wv][lane] = key;                 // lanes 49..63 write junk to unread slots
    int rd = 0;
    const uint4* kr = (const uint4*)ksh[wv];
#pragma unroll
    for (int j = 0; j < 12; j++) {       // keys 0..47
      uint4 q = kr[j];
      rd += (q.x > key); rd += (q.y > key); rd += (q.z > key); rd += (q.w > key);
    }
    rd += (ksh[wv][48] > key);
    if (lact) {
      if (rd < 9)   posa = v * cp;                     // top-9 most similar
      if (rd >= 41) nega = (1.f - v) * (1.f - cp);     // bottom-8 (rank_asc = 48-rd < 8)
    }
    cntW = 1.f;
  }

  // butterfly reduce 4 float sums
#pragma unroll
  for (int off = 32; off; off >>= 1) {
    psum += __shfl_xor(psum, off); ssum += __shfl_xor(ssum, off);
    posa += __shfl_xor(posa, off); nega += __shfl_xor(nega, off);
  }
  if (lane == 0) {
    sacc[wv][0] = psum;  sacc[wv][1] = pcntW; sacc[wv][2] = ssum;
    sacc[wv][3] = posa;  sacc[wv][4] = nega;  sacc[wv][5] = vcntW;
    sacc[wv][6] = cntW;  sacc[wv][7] = 0.f;
  }
  __syncthreads();
  if (t < 8) {
    partials[(size_t)bid * 8 + t] = sacc[0][t] + sacc[1][t] + sacc[2][t] + sacc[3][t];
  }
}

// ---------- F: reduce 8192 partials, combine ----------
__global__ __launch_bounds__(256) void finish_kernel(
    const float* __restrict__ partials, float* __restrict__ out) {
  int t = threadIdx.x, lane = t & 63, wv = t >> 6;
  float s0=0,s1=0,s2=0,s3=0,s4=0,s5=0,s6=0;
  for (int r = t; r < 8192; r += 256) {
    const float4* p = (const float4*)(partials + (size_t)r * 8);
    float4 x = p[0], y = p[1];
    s0 += x.x; s1 += x.y; s2 += x.z; s3 += x.w;
    s4 += y.x; s5 += y.y; s6 += y.z;
  }
#pragma unroll
  for (int off = 32; off; off >>= 1) {
    s0 += __shfl_xor(s0, off); s1 += __shfl_xor(s1, off);
    s2 += __shfl_xor(s2, off); s3 += __shfl_xor(s3, off);
    s4 += __shfl_xor(s4, off); s5 += __shfl_xor(s5, off);
    s6 += __shfl_xor(s6, off);
  }
  __shared__ float sacc[4][8];
  if (lane == 0) {
    sacc[wv][0]=s0; sacc[wv][1]=s1; sacc[wv][2]=s2; sacc[wv][3]=s3;
    sacc[wv][4]=s4; sacc[wv][5]=s5; sacc[wv][6]=s6;
  }
  __syncthreads();
  if (t == 0) {
    float a[7];
#pragma unroll
    for (int c = 0; c < 7; c++) a[c] = sacc[0][c] + sacc[1][c] + sacc[2][c] + sacc[3][c];
    float psum = a[0], pcnt = a[1], ssum = a[2];
    float posa = a[3], nega = a[4], vcnt = a[5], cnt = a[6];
    float nsum = ssum - psum;
    float ncnt = 49.f * vcnt - pcnt;
    out[0] = -(psum / fmaxf(pcnt, 1.0f));
    out[1] =  (nsum / fmaxf(ncnt, 1.0f));
    out[2] = -(posa / fmaxf(9.0f * cnt, 1.0f));
    out[3] = -(nega / fmaxf(8.0f * cnt, 1.0f));
  }
}

extern "C" void kernel_launch(void* const* d_in, const int* in_sizes, int n_in,
                              void* d_out, int out_size, void* d_ws, size_t ws_size,
                              hipStream_t stream) {
  const float* logits = (const float*)d_in[0];
  const int*   gt     = (const int*)  d_in[1];
  const float* xema   = (const float*)d_in[2];
  const float* xsrc   = (const float*)d_in[3];
  const float* mix    = (const float*)d_in[4];
  float* out = (float*)d_out;

  float* partials = (float*)d_ws;                                 // 8192*8 f32 = 256 KB
  u16* fsrc = (u16*)((char*)d_ws + 8192 * 8 * sizeof(float));     // Bb*BPIX*FSTR f16 ~= 4.03 MB
  u16* fema = fsrc + (size_t)Bb * BPIX * FSTR;                    // 4.03 MB
  u16* pt   = fema + (size_t)Bb * BPIX * FSTR;                    // Bb*BPIX*PSTR f16 ~= 2.02 MB

  pre_kernel<<<1152, 256, 0, stream>>>(logits, xsrc, xema, fsrc, fema, pt);
  st_kernel<<<8192, 256, 0, stream>>>(fsrc, fema, pt, gt, mix, partials);
  finish_kernel<<<1, 256, 0, stream>>>(partials, out);
}

// Round 9
// 40.265 us; speedup vs baseline: 1.6501x; 1.6501x over previous
//
#include <hip/hip_runtime.h>
#include <math.h>

typedef unsigned short u16;
typedef unsigned int   u32;
typedef unsigned long long u64;

#define Cc   19
#define HWs  16384
#define NPIX 32768
#define EPSf 1e-8f
#define FSTR 64               // feature vector: 128 B, line-aligned, linear [b][h][w] layout
#define PSTR 32               // prob vector: 64 B (19 real, pad 0)
#define NV   196              // 14x14 halo vectors per 8x8 tile
#define NTILE 512             // 2 * 16 * 16 tiles

typedef _Float16 h2 __attribute__((ext_vector_type(2)));

__device__ inline float fd(u32 a, u32 b, float c) {
  h2 ha = __builtin_bit_cast(h2, a);
  h2 hb = __builtin_bit_cast(h2, b);
#if __has_builtin(__builtin_amdgcn_fdot2)
  return __builtin_amdgcn_fdot2(ha, hb, c, false);
#else
  return c + (float)ha[0] * (float)hb[0] + (float)ha[1] * (float)hb[1];
#endif
}

__device__ inline u32 pk(float a, float b) {
  h2 h; h[0] = (_Float16)a; h[1] = (_Float16)b;
  return __builtin_bit_cast(u32, h);
}

// ---------- PRE: feat normalize+transpose (blocks 0..1023) | softmax (1024..1151) ----------
__global__ __launch_bounds__(256) void pre_kernel(
    const float* __restrict__ logits,
    const float* __restrict__ xsrc, const float* __restrict__ xema,
    u16* __restrict__ osrc, u16* __restrict__ oema, u16* __restrict__ pt) {
  __shared__ float smem[5376];
  int bid = blockIdx.x;
  int t = threadIdx.x;

  if (bid < 1024) {
    float* tile = smem;                 // 64*65
    float* part = smem + 4160;          // 256
    float* invn = smem + 4416;          // 64
    int xb = bid & 255, b = (bid >> 8) & 1, z = bid >> 9;
    const float* in = z ? xema : xsrc;
    u16* out = z ? oema : osrc;
    int pix0 = xb * 64;
    int w = t >> 6, l = t & 63;

    const float* src = in + (size_t)b * 64 * HWs + pix0;
#pragma unroll
    for (int cc = 0; cc < 16; cc++) {
      int c = cc * 4 + w;
      tile[c * 65 + l] = src[(size_t)c * HWs + l];
    }
    __syncthreads();
    float s = 0.f;
#pragma unroll
    for (int c = w * 16; c < w * 16 + 16; c++) { float a = tile[c * 65 + l]; s += a * a; }
    part[w * 64 + l] = s;
    __syncthreads();
    if (t < 64) {
      float n = part[t] + part[64 + t] + part[128 + t] + part[192 + t];
      invn[t] = 1.0f / fmaxf(sqrtf(n), EPSf);
    }
    __syncthreads();
    for (int i = t; i < 512; i += 256) {
      int px = i >> 3, q = i & 7;
      float iv = invn[px];
      float v[8];
#pragma unroll
      for (int k = 0; k < 8; k++) v[k] = tile[(q * 8 + k) * 65 + px] * iv;
      uint4 u = make_uint4(pk(v[0], v[1]), pk(v[2], v[3]), pk(v[4], v[5]), pk(v[6], v[7]));
      *((uint4*)(out + (size_t)(b * HWs + pix0 + px) * FSTR) + q) = u;
    }
  } else {
    float* lp = smem;                   // 256*21
    int pb = bid - 1024;
    int gpix = pb * 256 + t;
    int b = gpix >> 14, hw = gpix & (HWs - 1);
    const float* lg = logits + (size_t)b * Cc * HWs + hw;
    float v[Cc]; float m = -INFINITY;
#pragma unroll
    for (int c = 0; c < Cc; c++) { v[c] = lg[(size_t)c * HWs]; m = fmaxf(m, v[c]); }
    float s = 0.f;
#pragma unroll
    for (int c = 0; c < Cc; c++) { v[c] = expf(v[c] - m); s += v[c]; }
    float inv = 1.0f / s;
#pragma unroll
    for (int c = 0; c < Cc; c++) lp[t * 21 + c] = v[c] * inv;
    __syncthreads();
    u16* ob = pt + (size_t)pb * 256 * PSTR;
    for (int i = t; i < 1024; i += 256) {
      int px = i >> 2, q = i & 3;
      float v8[8];
#pragma unroll
      for (int k = 0; k < 8; k++) {
        int c = q * 8 + k;
        v8[k] = (c < Cc) ? lp[px * 21 + c] : 0.f;
      }
      uint4 u = make_uint4(pk(v8[0], v8[1]), pk(v8[2], v8[3]), pk(v8[4], v8[5]), pk(v8[6], v8[7]));
      *((uint4*)(ob + (size_t)px * PSTR) + q) = u;
    }
  }
}

// ---------- ST: LDS-staged 8x8 tile, wave = tile row ----------
__global__ __launch_bounds__(512, 2) void st_kernel(
    const u16* __restrict__ fsrc, const u16* __restrict__ fema,
    const u16* __restrict__ pt, const int* __restrict__ gt,
    const float* __restrict__ mix, float* __restrict__ partials) {
  __shared__ uint4 fbuf[2352];          // A: fsrc tile (1568 gran). B: fema (1568) + probs (784)
  __shared__ int   gtt[NV];
  __shared__ u32   ksh[8][64];
  __shared__ float sacc[8][8];

  int bid = blockIdx.x;
  int swz = ((bid & 7) << 6) | (bid >> 3);     // 512 % 8 == 0: bijective XCD swizzle
  int t = threadIdx.x, wv = t >> 6, lane = t & 63;
  int b  = swz >> 8;
  int th = (swz >> 4) & 15, tw = swz & 15;
  int h0 = th << 3, w0 = tw << 3;

  int nr = lane / 7, nc = lane - nr * 7;       // neighbor offsets (lane < 49)
  bool lact = lane < 49;

  // ---- phase A staging: fsrc tile (swizzled granules) + gt tile (zero-padded) ----
  const uint4* FS = (const uint4*)fsrc;
  for (int i = t; i < 1568; i += 512) {
    int vec = i >> 3, q = i & 7;
    int r = vec / 14, c = vec - r * 14;
    int gh = h0 + r - 3, gw = w0 + c - 3;
    uint4 d = make_uint4(0u, 0u, 0u, 0u);
    if (((unsigned)gh < 128u) && ((unsigned)gw < 128u))
      d = FS[((size_t)((b << 14) | (gh << 7) | gw) << 3) + q];
    fbuf[(vec << 3) | (q ^ (vec & 7))] = d;
  }
  for (int i = t; i < NV; i += 512) {
    int r = i / 14, c = i - r * 14;
    int gh = h0 + r - 3, gw = w0 + c - 3;
    int g = 0;
    if (((unsigned)gh < 128u) && ((unsigned)gw < 128u))
      g = gt[(b << 14) | (gh << 7) | gw];
    gtt[i] = g;
  }
  __syncthreads();

  float psum = 0, ssum = 0, posa = 0, nega = 0, pcntW = 0, vcntW = 0, cntW = 0;

  // ---- phase A compute: source sims (wave wv owns tile row wv) ----
  for (int tc = 0; tc < 8; ++tc) {
    int vc = (wv + 3) * 14 + (tc + 3);
    int gtc = gtt[vc];                          // wave-uniform broadcast
    if (gtc != 255) {
      int vn = lact ? ((wv + nr) * 14 + (tc + nc)) : vc;
      bool inb2 = lact && ((unsigned)(h0 + wv + nr - 3) < 128u)
                       && ((unsigned)(w0 + tc + nc - 3) < 128u);
      int vb = vn << 3, sx = vn & 7;
      int cb = vc << 3, sc = vc & 7;
      float d0 = 0, d1 = 0, d2 = 0, d3 = 0;
#pragma unroll
      for (int q = 0; q < 8; q += 4) {
        uint4 nA = fbuf[vb | ((q    ) ^ sx)];
        uint4 nB = fbuf[vb | ((q + 1) ^ sx)];
        uint4 nC = fbuf[vb | ((q + 2) ^ sx)];
        uint4 nD = fbuf[vb | ((q + 3) ^ sx)];
        uint4 cA = fbuf[cb | ((q    ) ^ sc)];
        uint4 cB = fbuf[cb | ((q + 1) ^ sc)];
        uint4 cC = fbuf[cb | ((q + 2) ^ sc)];
        uint4 cD = fbuf[cb | ((q + 3) ^ sc)];
        d0 = fd(cA.x,nA.x,d0); d0 = fd(cA.y,nA.y,d0); d0 = fd(cA.z,nA.z,d0); d0 = fd(cA.w,nA.w,d0);
        d1 = fd(cB.x,nB.x,d1); d1 = fd(cB.y,nB.y,d1); d1 = fd(cB.z,nB.z,d1); d1 = fd(cB.w,nB.w,d1);
        d2 = fd(cC.x,nC.x,d2); d2 = fd(cC.y,nC.y,d2); d2 = fd(cC.z,nC.z,d2); d2 = fd(cC.w,nC.w,d2);
        d3 = fd(cD.x,nD.x,d3); d3 = fd(cD.y,nD.y,d3); d3 = fd(cD.z,nD.z,d3); d3 = fd(cD.w,nD.w,d3);
      }
      float sims = inb2 ? ((d0 + d1) + (d2 + d3)) : 0.f;   // staged zeros -> 0 anyway
      int gtn = gtt[vn];                                   // staged zero for OOB (ref zero-pad)
      bool pos = (gtn == gtc);
      if (lact) { ssum += sims; if (pos) psum += sims; }
      u64 mk = __ballot(lact && pos);
      pcntW += (float)__popcll(mk);
      vcntW += 1.f;
    }
  }
  __syncthreads();

  // ---- phase B staging: fema tile + prob tile ----
  const uint4* FE = (const uint4*)fema;
  for (int i = t; i < 1568; i += 512) {
    int vec = i >> 3, q = i & 7;
    int r = vec / 14, c = vec - r * 14;
    int gh = h0 + r - 3, gw = w0 + c - 3;
    uint4 d = make_uint4(0u, 0u, 0u, 0u);
    if (((unsigned)gh < 128u) && ((unsigned)gw < 128u))
      d = FE[((size_t)((b << 14) | (gh << 7) | gw) << 3) + q];
    fbuf[(vec << 3) | (q ^ (vec & 7))] = d;
  }
  const uint4* PT4 = (const uint4*)pt;
  for (int i = t; i < 784; i += 512) {
    int vec = i >> 2, q = i & 3;
    int r = vec / 14, c = vec - r * 14;
    int gh = h0 + r - 3, gw = w0 + c - 3;
    uint4 d = make_uint4(0u, 0u, 0u, 0u);
    if (((unsigned)gh < 128u) && ((unsigned)gw < 128u))
      d = PT4[((size_t)((b << 14) | (gh << 7) | gw) << 2) + q];
    fbuf[1568 + ((vec << 2) | (q ^ (vec & 3)))] = d;
  }
  __syncthreads();

  // ---- phase B compute: target top-k ----
  for (int tc = 0; tc < 8; ++tc) {
    int h = h0 + wv, w = w0 + tc;
    float mixv = mix[(b << 14) | (h << 7) | w];          // wave-uniform
    if (mixv < 0.5f) {
      int vc = (wv + 3) * 14 + (tc + 3);
      int vn = lact ? ((wv + nr) * 14 + (tc + nc)) : vc;
      bool inb2 = lact && ((unsigned)(h + nr - 3) < 128u)
                       && ((unsigned)(w + nc - 3) < 128u);
      int vb = vn << 3, sx = vn & 7;
      int cb = vc << 3, sc = vc & 7;
      float d0 = 0, d1 = 0, d2 = 0, d3 = 0;
#pragma unroll
      for (int q = 0; q < 8; q += 4) {
        uint4 nA = fbuf[vb | ((q    ) ^ sx)];
        uint4 nB = fbuf[vb | ((q + 1) ^ sx)];
        uint4 nC = fbuf[vb | ((q + 2) ^ sx)];
        uint4 nD = fbuf[vb | ((q + 3) ^ sx)];
        uint4 cA = fbuf[cb | ((q    ) ^ sc)];
        uint4 cB = fbuf[cb | ((q + 1) ^ sc)];
        uint4 cC = fbuf[cb | ((q + 2) ^ sc)];
        uint4 cD = fbuf[cb | ((q + 3) ^ sc)];
        d0 = fd(cA.x,nA.x,d0); d0 = fd(cA.y,nA.y,d0); d0 = fd(cA.z,nA.z,d0); d0 = fd(cA.w,nA.w,d0);
        d1 = fd(cB.x,nB.x,d1); d1 = fd(cB.y,nB.y,d1); d1 = fd(cB.z,nB.z,d1); d1 = fd(cB.w,nB.w,d1);
        d2 = fd(cC.x,nC.x,d2); d2 = fd(cC.y,nC.y,d2); d2 = fd(cC.z,nC.z,d2); d2 = fd(cC.w,nC.w,d2);
        d3 = fd(cD.x,nD.x,d3); d3 = fd(cD.y,nD.y,d3); d3 = fd(cD.z,nD.z,d3); d3 = fd(cD.w,nD.w,d3);
      }
      float dote = (d0 + d1) + (d2 + d3);

      int pvb = vn << 2, psx = vn & 3;
      int pcb = vc << 2, psc = vc & 3;
      uint4 pA = fbuf[1568 + (pvb | (0 ^ psx))];
      uint4 pB = fbuf[1568 + (pvb | (1 ^ psx))];
      uint4 pC = fbuf[1568 + (pvb | (2 ^ psx))];
      uint4 qA = fbuf[1568 + (pcb | (0 ^ psc))];
      uint4 qB = fbuf[1568 + (pcb | (1 ^ psc))];
      uint4 qC = fbuf[1568 + (pcb | (2 ^ psc))];
      float p0 = 0, p1 = 0, p2 = 0;
      p0 = fd(qA.x,pA.x,p0); p0 = fd(qA.y,pA.y,p0); p0 = fd(qA.z,pA.z,p0); p0 = fd(qA.w,pA.w,p0);
      p1 = fd(qB.x,pB.x,p1); p1 = fd(qB.y,pB.y,p1); p1 = fd(qB.z,pB.z,p1); p1 = fd(qB.w,pB.w,p1);
      p2 = fd(qC.x,pC.x,p2); p2 = fd(qC.y,pC.y,p2); p2 = fd(qC.z,pC.z,p2); p2 = fd(qC.w,pC.w,p2);
      float dotp = (p0 + p1) + p2;

      float v  = inb2 ? dote : 0.f;
      float cp = inb2 ? dotp : (1.0f / 19.f);             // OOB: uniform softmax dot

      // u32 sortable key: top-26 monotone float bits | lane (distinct)
      u32 bits = __float_as_uint(v);
      u32 mono = (bits & 0x80000000u) ? ~bits : (bits | 0x80000000u);
      u32 key = (mono & 0xFFFFFFC0u) | (u32)lane;
      ksh[wv][lane] = key;
      int rd = 0;
      const uint4* kr = (const uint4*)ksh[wv];
#pragma unroll
      for (int j = 0; j < 12; j++) {
        uint4 qq = kr[j];
        rd += (qq.x > key); rd += (qq.y > key); rd += (qq.z > key); rd += (qq.w > key);
      }
      rd += (ksh[wv][48] > key);
      if (lact) {
        if (rd < 9)   posa += v * cp;                     // top-9 most similar
        if (rd >= 41) nega += (1.f - v) * (1.f - cp);     // bottom-8 of 49
      }
      cntW += 1.f;
    }
  }

  // ---- reduce ----
#pragma unroll
  for (int off = 32; off; off >>= 1) {
    psum += __shfl_xor(psum, off); ssum += __shfl_xor(ssum, off);
    posa += __shfl_xor(posa, off); nega += __shfl_xor(nega, off);
  }
  if (lane == 0) {
    sacc[wv][0] = psum;  sacc[wv][1] = pcntW; sacc[wv][2] = ssum;
    sacc[wv][3] = posa;  sacc[wv][4] = nega;  sacc[wv][5] = vcntW;
    sacc[wv][6] = cntW;  sacc[wv][7] = 0.f;
  }
  __syncthreads();
  if (t < 8) {
    float s = 0.f;
#pragma unroll
    for (int k = 0; k < 8; k++) s += sacc[k][t];
    partials[(size_t)bid * 8 + t] = s;
  }
}

// ---------- F: reduce NTILE partials, combine ----------
__global__ __launch_bounds__(256) void finish_kernel(
    const float* __restrict__ partials, float* __restrict__ out) {
  int t = threadIdx.x, lane = t & 63, wv = t >> 6;
  float s0=0,s1=0,s2=0,s3=0,s4=0,s5=0,s6=0;
  for (int r = t; r < NTILE; r += 256) {
    const float4* p = (const float4*)(partials + (size_t)r * 8);
    float4 x = p[0], y = p[1];
    s0 += x.x; s1 += x.y; s2 += x.z; s3 += x.w;
    s4 += y.x; s5 += y.y; s6 += y.z;
  }
#pragma unroll
  for (int off = 32; off; off >>= 1) {
    s0 += __shfl_xor(s0, off); s1 += __shfl_xor(s1, off);
    s2 += __shfl_xor(s2, off); s3 += __shfl_xor(s3, off);
    s4 += __shfl_xor(s4, off); s5 += __shfl_xor(s5, off);
    s6 += __shfl_xor(s6, off);
  }
  __shared__ float sacc[4][8];
  if (lane == 0) {
    sacc[wv][0]=s0; sacc[wv][1]=s1; sacc[wv][2]=s2; sacc[wv][3]=s3;
    sacc[wv][4]=s4; sacc[wv][5]=s5; sacc[wv][6]=s6;
  }
  __syncthreads();
  if (t == 0) {
    float a[7];
#pragma unroll
    for (int c = 0; c < 7; c++) a[c] = sacc[0][c] + sacc[1][c] + sacc[2][c] + sacc[3][c];
    float psum = a[0], pcnt = a[1], ssum = a[2];
    float posa = a[3], nega = a[4], vcnt = a[5], cnt = a[6];
    float nsum = ssum - psum;
    float ncnt = 49.f * vcnt - pcnt;
    out[0] = -(psum / fmaxf(pcnt, 1.0f));
    out[1] =  (nsum / fmaxf(ncnt, 1.0f));
    out[2] = -(posa / fmaxf(9.0f * cnt, 1.0f));
    out[3] = -(nega / fmaxf(8.0f * cnt, 1.0f));
  }
}

extern "C" void kernel_launch(void* const* d_in, const int* in_sizes, int n_in,
                              void* d_out, int out_size, void* d_ws, size_t ws_size,
                              hipStream_t stream) {
  const float* logits = (const float*)d_in[0];
  const int*   gt     = (const int*)  d_in[1];
  const float* xema   = (const float*)d_in[2];
  const float* xsrc   = (const float*)d_in[3];
  const float* mix    = (const float*)d_in[4];
  float* out = (float*)d_out;

  float* partials = (float*)d_ws;                                 // NTILE*8 f32 = 16 KB
  u16* fsrc = (u16*)((char*)d_ws + NTILE * 8 * sizeof(float));    // NPIX*FSTR f16 = 4 MB
  u16* fema = fsrc + (size_t)NPIX * FSTR;                         // 4 MB
  u16* pt   = fema + (size_t)NPIX * FSTR;                         // NPIX*PSTR f16 = 2 MB

  pre_kernel<<<1152, 256, 0, stream>>>(logits, xsrc, xema, fsrc, fema, pt);
  st_kernel<<<NTILE, 512, 0, stream>>>(fsrc, fema, pt, gt, mix, partials);
  finish_kernel<<<1, 256, 0, stream>>>(partials, out);
}

// Round 10
// 39.269 us; speedup vs baseline: 1.6919x; 1.0254x over previous
//
#include <hip/hip_runtime.h>
#include <math.h>

typedef unsigned short u16;
typedef unsigned int   u32;
typedef unsigned long long u64;

#define Cc   19
#define HWs  16384
#define NPIX 32768
#define FSTR 64               // feature vector: 128 B (8 granules), line-aligned
#define PSTR 24               // prob vector: 48 B (3 granules; 19 real + 5 zero pad)
#define NV   196              // 14x14 halo vectors per 8x8 tile
#define NTILE 512             // 2 * 16 * 16 tiles
#define UNIF19 0x2ABD2ABDu    // f16x2(1/19, 1/19)

typedef _Float16 h2 __attribute__((ext_vector_type(2)));

__device__ inline float fd(u32 a, u32 b, float c) {
  h2 ha = __builtin_bit_cast(h2, a);
  h2 hb = __builtin_bit_cast(h2, b);
#if __has_builtin(__builtin_amdgcn_fdot2)
  return __builtin_amdgcn_fdot2(ha, hb, c, false);
#else
  return c + (float)ha[0] * (float)hb[0] + (float)ha[1] * (float)hb[1];
#endif
}

__device__ inline u32 pk(float a, float b) {
  h2 h; h[0] = (_Float16)a; h[1] = (_Float16)b;
  return __builtin_bit_cast(u32, h);
}

// ---------- PRE: feat normalize+transpose (blocks 0..1023) | softmax (1024..1151) ----------
__global__ __launch_bounds__(256) void pre_kernel(
    const float* __restrict__ logits,
    const float* __restrict__ xsrc, const float* __restrict__ xema,
    u16* __restrict__ osrc, u16* __restrict__ oema, u16* __restrict__ pt) {
  __shared__ float smem[5376];
  int bid = blockIdx.x;
  int t = threadIdx.x;

  if (bid < 1024) {
    float* tile = smem;                 // 64*65
    float* part = smem + 4160;          // 256
    float* invn = smem + 4416;          // 64
    int xb = bid & 255, b = (bid >> 8) & 1, z = bid >> 9;
    const float* in = z ? xema : xsrc;
    u16* out = z ? oema : osrc;
    int pix0 = xb * 64;
    int w = t >> 6, l = t & 63;

    const float* src = in + (size_t)b * 64 * HWs + pix0;
#pragma unroll
    for (int cc = 0; cc < 16; cc++) {
      int c = cc * 4 + w;
      tile[c * 65 + l] = src[(size_t)c * HWs + l];
    }
    __syncthreads();
    float s = 0.f;
#pragma unroll
    for (int c = w * 16; c < w * 16 + 16; c++) { float a = tile[c * 65 + l]; s += a * a; }
    part[w * 64 + l] = s;
    __syncthreads();
    if (t < 64) {
      float n = part[t] + part[64 + t] + part[128 + t] + part[192 + t];
      invn[t] = rsqrtf(fmaxf(n, 1e-16f));   // == 1/max(sqrt(n),1e-8) in practice
    }
    __syncthreads();
    for (int i = t; i < 512; i += 256) {
      int px = i >> 3, q = i & 7;
      float iv = invn[px];
      float v[8];
#pragma unroll
      for (int k = 0; k < 8; k++) v[k] = tile[(q * 8 + k) * 65 + px] * iv;
      uint4 u = make_uint4(pk(v[0], v[1]), pk(v[2], v[3]), pk(v[4], v[5]), pk(v[6], v[7]));
      *((uint4*)(out + (size_t)(b * HWs + pix0 + px) * FSTR) + q) = u;
    }
  } else {
    float* lp = smem;                   // 256*21
    int pb = bid - 1024;
    int gpix = pb * 256 + t;
    int b = gpix >> 14, hw = gpix & (HWs - 1);
    const float* lg = logits + (size_t)b * Cc * HWs + hw;
    float s = 0.f;
    float v[Cc];
#pragma unroll
    for (int c = 0; c < Cc; c++) { v[c] = __expf(lg[(size_t)c * HWs]); s += v[c]; }
    float inv = 1.0f / s;
#pragma unroll
    for (int c = 0; c < Cc; c++) lp[t * 21 + c] = v[c] * inv;
    __syncthreads();
    u16* ob = pt + (size_t)pb * 256 * PSTR;
    for (int i = t; i < 768; i += 256) {
      int px = i / 3, q = i - px * 3;
      float v8[8];
#pragma unroll
      for (int k = 0; k < 8; k++) {
        int c = q * 8 + k;
        v8[k] = (c < Cc) ? lp[px * 21 + c] : 0.f;
      }
      uint4 u = make_uint4(pk(v8[0], v8[1]), pk(v8[2], v8[3]), pk(v8[4], v8[5]), pk(v8[6], v8[7]));
      *((uint4*)(ob + (size_t)px * PSTR) + q) = u;
    }
  }
}

// ---------- ST: LDS-staged 8x8 tile, single staging phase, wave = tile row ----------
__global__ __launch_bounds__(512, 2) void st_kernel(
    const u16* __restrict__ fsrc, const u16* __restrict__ fema,
    const u16* __restrict__ pt, const int* __restrict__ gt,
    const float* __restrict__ mix, float* __restrict__ partials) {
  __shared__ uint4 fbuf[3724];   // [0,1568) fsrc | [1568,3136) fema | [3136,3724) probs
  __shared__ int   gtt[NV];
  __shared__ float mixs[64];
  __shared__ u32   ksh[8][64];
  __shared__ float sacc[8][8];

  int bid = blockIdx.x;
  int swz = ((bid & 7) << 6) | (bid >> 3);     // 512 % 8 == 0: bijective XCD swizzle
  int t = threadIdx.x, wv = t >> 6, lane = t & 63;
  int b  = swz >> 8;
  int th = (swz >> 4) & 15, tw = swz & 15;
  int h0 = th << 3, w0 = tw << 3;

  int nr = lane / 7, nc = lane - nr * 7;       // neighbor offsets (lane < 49)
  bool lact = lane < 49;

  // ---- single staging phase: fsrc + fema (swizzled granules), probs, gt, mix ----
  const uint4* FS = (const uint4*)fsrc;
  const uint4* FE = (const uint4*)fema;
  for (int i = t; i < 3136; i += 512) {
    int ii = (i >= 1568) ? (i - 1568) : i;
    int vec = ii >> 3, q = ii & 7;
    int r = vec / 14, c = vec - r * 14;
    int gh = h0 + r - 3, gw = w0 + c - 3;
    uint4 d = make_uint4(0u, 0u, 0u, 0u);
    if (((unsigned)gh < 128u) && ((unsigned)gw < 128u)) {
      size_t gidx = ((size_t)((b << 14) | (gh << 7) | gw) << 3) + q;
      d = (i >= 1568) ? FE[gidx] : FS[gidx];
    }
    fbuf[((i >= 1568) ? 1568 : 0) + ((vec << 3) | (q ^ (vec & 7)))] = d;
  }
  const uint4* PT3 = (const uint4*)pt;
  for (int i = t; i < 588; i += 512) {
    int vec = i / 3, q = i - vec * 3;
    int r = vec / 14, c = vec - r * 14;
    int gh = h0 + r - 3, gw = w0 + c - 3;
    uint4 d = make_uint4(UNIF19, UNIF19, UNIF19, UNIF19);   // OOB: uniform 1/19 probs
    if (((unsigned)gh < 128u) && ((unsigned)gw < 128u))
      d = PT3[(size_t)((b << 14) | (gh << 7) | gw) * 3 + q];
    fbuf[3136 + vec * 3 + q] = d;                           // stride-3: conflict-free
  }
  for (int i = t; i < NV; i += 512) {
    int r = i / 14, c = i - r * 14;
    int gh = h0 + r - 3, gw = w0 + c - 3;
    int g = 0;
    if (((unsigned)gh < 128u) && ((unsigned)gw < 128u))
      g = gt[(b << 14) | (gh << 7) | gw];
    gtt[i] = g;
  }
  if (t < 64) {
    int r = t >> 3, c = t & 7;
    mixs[t] = mix[(b << 14) | ((h0 + r) << 7) | (w0 + c)];
  }
  __syncthreads();

  float psum = 0, ssum = 0, posa = 0, nega = 0, pcntW = 0, vcntW = 0, cntW = 0;

  // ---- phase A compute: source sims (wave wv owns tile row wv) ----
  for (int tc = 0; tc < 8; ++tc) {
    int vc = (wv + 3) * 14 + (tc + 3);
    int gtc = gtt[vc];                          // wave-uniform broadcast
    if (gtc != 255) {
      int vn = lact ? ((wv + nr) * 14 + (tc + nc)) : vc;
      int vb = vn << 3, sx = vn & 7;
      int cb = vc << 3, sc = vc & 7;
      float d0 = 0, d1 = 0, d2 = 0, d3 = 0;
#pragma unroll
      for (int q = 0; q < 8; q += 4) {
        uint4 nA = fbuf[vb | ((q    ) ^ sx)];
        uint4 nB = fbuf[vb | ((q + 1) ^ sx)];
        uint4 nC = fbuf[vb | ((q + 2) ^ sx)];
        uint4 nD = fbuf[vb | ((q + 3) ^ sx)];
        uint4 cA = fbuf[cb | ((q    ) ^ sc)];
        uint4 cB = fbuf[cb | ((q + 1) ^ sc)];
        uint4 cC = fbuf[cb | ((q + 2) ^ sc)];
        uint4 cD = fbuf[cb | ((q + 3) ^ sc)];
        d0 = fd(cA.x,nA.x,d0); d0 = fd(cA.y,nA.y,d0); d0 = fd(cA.z,nA.z,d0); d0 = fd(cA.w,nA.w,d0);
        d1 = fd(cB.x,nB.x,d1); d1 = fd(cB.y,nB.y,d1); d1 = fd(cB.z,nB.z,d1); d1 = fd(cB.w,nB.w,d1);
        d2 = fd(cC.x,nC.x,d2); d2 = fd(cC.y,nC.y,d2); d2 = fd(cC.z,nC.z,d2); d2 = fd(cC.w,nC.w,d2);
        d3 = fd(cD.x,nD.x,d3); d3 = fd(cD.y,nD.y,d3); d3 = fd(cD.z,nD.z,d3); d3 = fd(cD.w,nD.w,d3);
      }
      float sims = (d0 + d1) + (d2 + d3);       // OOB: staged zeros -> 0 (ref zero-pad)
      int gtn = gtt[vn];                        // OOB: staged 0 (ref zero-pad)
      bool pos = (gtn == gtc);
      if (lact) { ssum += sims; if (pos) psum += sims; }
      u64 mk = __ballot(lact && pos);
      pcntW += (float)__popcll(mk);
      vcntW += 1.f;
    }
  }

  // ---- phase B compute: target top-k (no barrier needed; disjoint LDS reads) ----
  for (int tc = 0; tc < 8; ++tc) {
    if (mixs[(wv << 3) | tc] < 0.5f) {          // wave-uniform
      int vc = (wv + 3) * 14 + (tc + 3);
      int vn = lact ? ((wv + nr) * 14 + (tc + nc)) : vc;
      int vb = vn << 3, sx = vn & 7;
      int cb = vc << 3, sc = vc & 7;
      float d0 = 0, d1 = 0, d2 = 0, d3 = 0;
#pragma unroll
      for (int q = 0; q < 8; q += 4) {
        uint4 nA = fbuf[1568 + (vb | ((q    ) ^ sx))];
        uint4 nB = fbuf[1568 + (vb | ((q + 1) ^ sx))];
        uint4 nC = fbuf[1568 + (vb | ((q + 2) ^ sx))];
        uint4 nD = fbuf[1568 + (vb | ((q + 3) ^ sx))];
        uint4 cA = fbuf[1568 + (cb | ((q    ) ^ sc))];
        uint4 cB = fbuf[1568 + (cb | ((q + 1) ^ sc))];
        uint4 cC = fbuf[1568 + (cb | ((q + 2) ^ sc))];
        uint4 cD = fbuf[1568 + (cb | ((q + 3) ^ sc))];
        d0 = fd(cA.x,nA.x,d0); d0 = fd(cA.y,nA.y,d0); d0 = fd(cA.z,nA.z,d0); d0 = fd(cA.w,nA.w,d0);
        d1 = fd(cB.x,nB.x,d1); d1 = fd(cB.y,nB.y,d1); d1 = fd(cB.z,nB.z,d1); d1 = fd(cB.w,nB.w,d1);
        d2 = fd(cC.x,nC.x,d2); d2 = fd(cC.y,nC.y,d2); d2 = fd(cC.z,nC.z,d2); d2 = fd(cC.w,nC.w,d2);
        d3 = fd(cD.x,nD.x,d3); d3 = fd(cD.y,nD.y,d3); d3 = fd(cD.z,nD.z,d3); d3 = fd(cD.w,nD.w,d3);
      }
      float v = (d0 + d1) + (d2 + d3);          // OOB: staged zeros -> 0

      uint4 pA = fbuf[3136 + vn * 3 + 0];
      uint4 pB = fbuf[3136 + vn * 3 + 1];
      uint4 pC = fbuf[3136 + vn * 3 + 2];
      uint4 qA = fbuf[3136 + vc * 3 + 0];
      uint4 qB = fbuf[3136 + vc * 3 + 1];
      uint4 qC = fbuf[3136 + vc * 3 + 2];
      float p0 = 0, p1 = 0, p2 = 0;
      p0 = fd(qA.x,pA.x,p0); p0 = fd(qA.y,pA.y,p0); p0 = fd(qA.z,pA.z,p0); p0 = fd(qA.w,pA.w,p0);
      p1 = fd(qB.x,pB.x,p1); p1 = fd(qB.y,pB.y,p1); p1 = fd(qB.z,pB.z,p1); p1 = fd(qB.w,pB.w,p1);
      p2 = fd(qC.x,pC.x,p2); p2 = fd(qC.y,pC.y,p2); p2 = fd(qC.z,pC.z,p2); p2 = fd(qC.w,pC.w,p2);
      float cp = (p0 + p1) + p2;                // OOB: staged 1/19 pattern -> 1/19 (center pads 0)

      // u32 sortable key: top-26 monotone float bits | lane (distinct)
      u32 bits = __float_as_uint(v);
      u32 mono = (bits & 0x80000000u) ? ~bits : (bits | 0x80000000u);
      u32 key = (mono & 0xFFFFFFC0u) | (u32)lane;
      ksh[wv][lane] = key;
      int rd = 0;
      const uint4* kr = (const uint4*)ksh[wv];
#pragma unroll
      for (int j = 0; j < 12; j++) {
        uint4 qq = kr[j];
        rd += (qq.x > key); rd += (qq.y > key); rd += (qq.z > key); rd += (qq.w > key);
      }
      rd += (ksh[wv][48] > key);
      if (lact) {
        if (rd < 9)   posa += v * cp;                     // top-9 most similar
        if (rd >= 41) nega += (1.f - v) * (1.f - cp);     // bottom-8 of 49
      }
      cntW += 1.f;
    }
  }

  // ---- reduce ----
#pragma unroll
  for (int off = 32; off; off >>= 1) {
    psum += __shfl_xor(psum, off); ssum += __shfl_xor(ssum, off);
    posa += __shfl_xor(posa, off); nega += __shfl_xor(nega, off);
  }
  if (lane == 0) {
    sacc[wv][0] = psum;  sacc[wv][1] = pcntW; sacc[wv][2] = ssum;
    sacc[wv][3] = posa;  sacc[wv][4] = nega;  sacc[wv][5] = vcntW;
    sacc[wv][6] = cntW;  sacc[wv][7] = 0.f;
  }
  __syncthreads();
  if (t < 8) {
    float s = 0.f;
#pragma unroll
    for (int k = 0; k < 8; k++) s += sacc[k][t];
    partials[(size_t)bid * 8 + t] = s;
  }
}

// ---------- F: reduce NTILE partials, combine ----------
__global__ __launch_bounds__(256) void finish_kernel(
    const float* __restrict__ partials, float* __restrict__ out) {
  int t = threadIdx.x, lane = t & 63, wv = t >> 6;
  float s0=0,s1=0,s2=0,s3=0,s4=0,s5=0,s6=0;
  for (int r = t; r < NTILE; r += 256) {
    const float4* p = (const float4*)(partials + (size_t)r * 8);
    float4 x = p[0], y = p[1];
    s0 += x.x; s1 += x.y; s2 += x.z; s3 += x.w;
    s4 += y.x; s5 += y.y; s6 += y.z;
  }
#pragma unroll
  for (int off = 32; off; off >>= 1) {
    s0 += __shfl_xor(s0, off); s1 += __shfl_xor(s1, off);
    s2 += __shfl_xor(s2, off); s3 += __shfl_xor(s3, off);
    s4 += __shfl_xor(s4, off); s5 += __shfl_xor(s5, off);
    s6 += __shfl_xor(s6, off);
  }
  __shared__ float sacc[4][8];
  if (lane == 0) {
    sacc[wv][0]=s0; sacc[wv][1]=s1; sacc[wv][2]=s2; sacc[wv][3]=s3;
    sacc[wv][4]=s4; sacc[wv][5]=s5; sacc[wv][6]=s6;
  }
  __syncthreads();
  if (t == 0) {
    float a[7];
#pragma unroll
    for (int c = 0; c < 7; c++) a[c] = sacc[0][c] + sacc[1][c] + sacc[2][c] + sacc[3][c];
    float psum = a[0], pcnt = a[1], ssum = a[2];
    float posa = a[3], nega = a[4], vcnt = a[5], cnt = a[6];
    float nsum = ssum - psum;
    float ncnt = 49.f * vcnt - pcnt;
    out[0] = -(psum / fmaxf(pcnt, 1.0f));
    out[1] =  (nsum / fmaxf(ncnt, 1.0f));
    out[2] = -(posa / fmaxf(9.0f * cnt, 1.0f));
    out[3] = -(nega / fmaxf(8.0f * cnt, 1.0f));
  }
}

extern "C" void kernel_launch(void* const* d_in, const int* in_sizes, int n_in,
                              void* d_out, int out_size, void* d_ws, size_t ws_size,
                              hipStream_t stream) {
  const float* logits = (const float*)d_in[0];
  const int*   gt     = (const int*)  d_in[1];
  const float* xema   = (const float*)d_in[2];
  const float* xsrc   = (const float*)d_in[3];
  const float* mix    = (const float*)d_in[4];
  float* out = (float*)d_out;

  float* partials = (float*)d_ws;                                 // NTILE*8 f32 = 16 KB
  u16* fsrc = (u16*)((char*)d_ws + NTILE * 8 * sizeof(float));    // NPIX*FSTR f16 = 4 MB
  u16* fema = fsrc + (size_t)NPIX * FSTR;                         // 4 MB
  u16* pt   = fema + (size_t)NPIX * FSTR;                         // NPIX*PSTR f16 = 1.5 MB

  pre_kernel<<<1152, 256, 0, stream>>>(logits, xsrc, xema, fsrc, fema, pt);
  st_kernel<<<NTILE, 512, 0, stream>>>(fsrc, fema, pt, gt, mix, partials);
  finish_kernel<<<1, 256, 0, stream>>>(partials, out);
}

// Round 11
// 38.466 us; speedup vs baseline: 1.7273x; 1.0209x over previous
//
#include <hip/hip_runtime.h>
#include <math.h>

typedef unsigned short u16;
typedef unsigned int   u32;
typedef unsigned long long u64;

#define Cc   19
#define HWs  16384
#define NPIX 32768
#define FSTR 64               // feature vector: 128 B (8 granules), line-aligned
#define PSTR 24               // prob vector: 48 B (3 granules; 19 real + 5 zero pad)
#define NV   196              // 14x14 halo vectors per 8x8 tile
#define NTILE 512             // 2 * 16 * 16 tiles
#define UNIF19 0x2ABD2ABDu    // f16x2(1/19, 1/19)

typedef _Float16 h2    __attribute__((ext_vector_type(2)));
typedef _Float16 half8 __attribute__((ext_vector_type(8)));
typedef float  floatx4 __attribute__((ext_vector_type(4)));

__device__ inline float fd(u32 a, u32 b, float c) {
  h2 ha = __builtin_bit_cast(h2, a);
  h2 hb = __builtin_bit_cast(h2, b);
#if __has_builtin(__builtin_amdgcn_fdot2)
  return __builtin_amdgcn_fdot2(ha, hb, c, false);
#else
  return c + (float)ha[0] * (float)hb[0] + (float)ha[1] * (float)hb[1];
#endif
}

__device__ inline u32 pk(float a, float b) {
  h2 h; h[0] = (_Float16)a; h[1] = (_Float16)b;
  return __builtin_bit_cast(u32, h);
}

// ---------- PRE: feat normalize+transpose (blocks 0..1023) | softmax (1024..1151) ----------
__global__ __launch_bounds__(256) void pre_kernel(
    const float* __restrict__ logits,
    const float* __restrict__ xsrc, const float* __restrict__ xema,
    u16* __restrict__ osrc, u16* __restrict__ oema, u16* __restrict__ pt) {
  __shared__ float smem[5376];
  int bid = blockIdx.x;
  int t = threadIdx.x;

  if (bid < 1024) {
    float* tile = smem;                 // 64*65
    float* part = smem + 4160;          // 256
    float* invn = smem + 4416;          // 64
    int xb = bid & 255, b = (bid >> 8) & 1, z = bid >> 9;
    const float* in = z ? xema : xsrc;
    u16* out = z ? oema : osrc;
    int pix0 = xb * 64;
    int w = t >> 6, l = t & 63;

    const float* src = in + (size_t)b * 64 * HWs + pix0;
#pragma unroll
    for (int cc = 0; cc < 16; cc++) {
      int c = cc * 4 + w;
      tile[c * 65 + l] = src[(size_t)c * HWs + l];
    }
    __syncthreads();
    float s = 0.f;
#pragma unroll
    for (int c = w * 16; c < w * 16 + 16; c++) { float a = tile[c * 65 + l]; s += a * a; }
    part[w * 64 + l] = s;
    __syncthreads();
    if (t < 64) {
      float n = part[t] + part[64 + t] + part[128 + t] + part[192 + t];
      invn[t] = rsqrtf(fmaxf(n, 1e-16f));
    }
    __syncthreads();
    for (int i = t; i < 512; i += 256) {
      int px = i >> 3, q = i & 7;
      float iv = invn[px];
      float v[8];
#pragma unroll
      for (int k = 0; k < 8; k++) v[k] = tile[(q * 8 + k) * 65 + px] * iv;
      uint4 u = make_uint4(pk(v[0], v[1]), pk(v[2], v[3]), pk(v[4], v[5]), pk(v[6], v[7]));
      *((uint4*)(out + (size_t)(b * HWs + pix0 + px) * FSTR) + q) = u;
    }
  } else {
    float* lp = smem;                   // 256*21
    int pb = bid - 1024;
    int gpix = pb * 256 + t;
    int b = gpix >> 14, hw = gpix & (HWs - 1);
    const float* lg = logits + (size_t)b * Cc * HWs + hw;
    float s = 0.f;
    float v[Cc];
#pragma unroll
    for (int c = 0; c < Cc; c++) { v[c] = __expf(lg[(size_t)c * HWs]); s += v[c]; }
    float inv = 1.0f / s;
#pragma unroll
    for (int c = 0; c < Cc; c++) lp[t * 21 + c] = v[c] * inv;
    __syncthreads();
    u16* ob = pt + (size_t)pb * 256 * PSTR;
    for (int i = t; i < 768; i += 256) {
      int px = i / 3, q = i - px * 3;
      float v8[8];
#pragma unroll
      for (int k = 0; k < 8; k++) {
        int c = q * 8 + k;
        v8[k] = (c < Cc) ? lp[px * 21 + c] : 0.f;
      }
      uint4 u = make_uint4(pk(v8[0], v8[1]), pk(v8[2], v8[3]), pk(v8[4], v8[5]), pk(v8[6], v8[7]));
      *((uint4*)(ob + (size_t)px * PSTR) + q) = u;
    }
  }
}

// ---------- ST: MFMA banded Gram + rank-select. 8x8 tile per block, 8 waves ----------
// Gram band per row-tile t (16 px = spatial rows 2t,2t+1): halo cols 28t .. 28t+112.
// Fragment pattern (verified B^T-GEMM layout): lane l reads granule (l>>4) of vector (l&15).
__global__ __launch_bounds__(512, 1) void st_kernel(
    const u16* __restrict__ fsrc, const u16* __restrict__ fema,
    const u16* __restrict__ pt, const int* __restrict__ gt,
    const float* __restrict__ mix, float* __restrict__ partials) {
  __shared__ uint4 fsb[1568];          // fsrc halo, XOR-swizzled granules
  __shared__ uint4 feb[1568];          // fema halo
  __shared__ uint4 prb[588];           // probs halo (3 granules, stride-3 linear)
  __shared__ float Csc[4][16][113];    // banded Gram scratch (reused src -> ema)
  __shared__ int   gtt[NV];
  __shared__ float mixs[64];
  __shared__ u32   ksh[8][64];
  __shared__ float sacc[8][8];

  int bid = blockIdx.x;
  int swz = ((bid & 7) << 6) | (bid >> 3);     // bijective XCD swizzle
  int t = threadIdx.x, wv = t >> 6, lane = t & 63;
  int b  = swz >> 8;
  int th = (swz >> 4) & 15, tw = swz & 15;
  int h0 = th << 3, w0 = tw << 3;

  int nr = lane / 7, nc = lane - nr * 7;       // neighbor offsets (lane < 49)
  bool lact = lane < 49;

  // ---- staging: fsrc + fema halos (swizzled), probs, gt, mix ----
  const uint4* FS = (const uint4*)fsrc;
  const uint4* FE = (const uint4*)fema;
  for (int i = t; i < 3136; i += 512) {
    int ii = (i >= 1568) ? (i - 1568) : i;
    int vec = ii >> 3, q = ii & 7;
    int r = vec / 14, c = vec - r * 14;
    int gh = h0 + r - 3, gw = w0 + c - 3;
    uint4 d = make_uint4(0u, 0u, 0u, 0u);
    if (((unsigned)gh < 128u) && ((unsigned)gw < 128u)) {
      size_t gidx = ((size_t)((b << 14) | (gh << 7) | gw) << 3) + q;
      d = (i >= 1568) ? FE[gidx] : FS[gidx];
    }
    (i >= 1568 ? feb : fsb)[(vec << 3) | (q ^ (vec & 7))] = d;
  }
  const uint4* PT3 = (const uint4*)pt;
  for (int i = t; i < 588; i += 512) {
    int vec = i / 3, q = i - vec * 3;
    int r = vec / 14, c = vec - r * 14;
    int gh = h0 + r - 3, gw = w0 + c - 3;
    uint4 d = make_uint4(UNIF19, UNIF19, UNIF19, UNIF19);   // OOB: uniform 1/19 probs
    if (((unsigned)gh < 128u) && ((unsigned)gw < 128u))
      d = PT3[(size_t)((b << 14) | (gh << 7) | gw) * 3 + q];
    prb[vec * 3 + q] = d;
  }
  for (int i = t; i < NV; i += 512) {
    int r = i / 14, c = i - r * 14;
    int gh = h0 + r - 3, gw = w0 + c - 3;
    int g = 0;
    if (((unsigned)gh < 128u) && ((unsigned)gw < 128u))
      g = gt[(b << 14) | (gh << 7) | gw];
    gtt[i] = g;
  }
  if (t < 64) {
    int r = t >> 3, c = t & 7;
    mixs[t] = mix[(b << 14) | ((h0 + r) << 7) | (w0 + c)];
  }
  __syncthreads();

  // ---- gram geometry: wave wv -> row-tile rt = wv>>1, col-half hf = wv&1 ----
  int rt = wv >> 1, hf = wv & 1;
  int p16 = lane & 15, gq = lane >> 4;
  int va = (2 * rt + (p16 >> 3) + 3) * 14 + ((p16 & 7) + 3);   // A vec = tile pixel p16
  int ntiles = hf ? 3 : 4;
  int cb0 = hf ? 64 : 0;                        // col offset within 112-band
  int vb0 = 28 * rt + cb0;                      // halo idx base of first col-tile

  // ---- gram (fsrc) -> Csc ----
  {
    half8 a0 = __builtin_bit_cast(half8, fsb[(va << 3) | ((gq    ) ^ (va & 7))]);
    half8 a1 = __builtin_bit_cast(half8, fsb[(va << 3) | ((gq + 4) ^ (va & 7))]);
    for (int ct = 0; ct < ntiles; ct++) {
      int vb = vb0 + ct * 16 + p16;
      half8 b0 = __builtin_bit_cast(half8, fsb[(vb << 3) | ((gq    ) ^ (vb & 7))]);
      half8 b1 = __builtin_bit_cast(half8, fsb[(vb << 3) | ((gq + 4) ^ (vb & 7))]);
      floatx4 acc = {0.f, 0.f, 0.f, 0.f};
      acc = __builtin_amdgcn_mfma_f32_16x16x32_f16(a0, b0, acc, 0, 0, 0);
      acc = __builtin_amdgcn_mfma_f32_16x16x32_f16(a1, b1, acc, 0, 0, 0);
      int row = gq << 2, col = cb0 + ct * 16 + p16;
#pragma unroll
      for (int r = 0; r < 4; r++) Csc[rt][row + r][col] = acc[r];   // C: col=lane&15, row=(lane>>4)*4+r
    }
  }
  __syncthreads();

  float psum = 0, ssum = 0, posa = 0, nega = 0, pcntW = 0, vcntW = 0, cntW = 0;
  int ri = wv & 1;                              // row within row-tile (== hf)

  // ---- epilogue A: source sums (wave wv owns spatial row wv) ----
  for (int tc = 0; tc < 8; ++tc) {
    int vcH = (wv + 3) * 14 + (tc + 3);
    int gtcv = gtt[vcH];
    if (gtcv != 255) {
      int cbi = lact ? ((ri + nr) * 14 + (tc + nc)) : 0;
      float sims = Csc[rt][ri * 8 + tc][cbi];   // OOB neighbors: zero vectors -> 0
      int vnH = lact ? ((wv + nr) * 14 + (tc + nc)) : vcH;
      int gtn = gtt[vnH];                       // OOB: staged 0 (ref zero-pad)
      bool pos = (gtn == gtcv);
      if (lact) { ssum += sims; if (pos) psum += sims; }
      u64 mk = __ballot(lact && pos);
      pcntW += (float)__popcll(mk);
      vcntW += 1.f;
    }
  }
  __syncthreads();                              // before Csc reuse

  // ---- gram (fema) -> Csc ----
  {
    half8 a0 = __builtin_bit_cast(half8, feb[(va << 3) | ((gq    ) ^ (va & 7))]);
    half8 a1 = __builtin_bit_cast(half8, feb[(va << 3) | ((gq + 4) ^ (va & 7))]);
    for (int ct = 0; ct < ntiles; ct++) {
      int vb = vb0 + ct * 16 + p16;
      half8 b0 = __builtin_bit_cast(half8, feb[(vb << 3) | ((gq    ) ^ (vb & 7))]);
      half8 b1 = __builtin_bit_cast(half8, feb[(vb << 3) | ((gq + 4) ^ (vb & 7))]);
      floatx4 acc = {0.f, 0.f, 0.f, 0.f};
      acc = __builtin_amdgcn_mfma_f32_16x16x32_f16(a0, b0, acc, 0, 0, 0);
      acc = __builtin_amdgcn_mfma_f32_16x16x32_f16(a1, b1, acc, 0, 0, 0);
      int row = gq << 2, col = cb0 + ct * 16 + p16;
#pragma unroll
      for (int r = 0; r < 4; r++) Csc[rt][row + r][col] = acc[r];
    }
  }
  __syncthreads();

  // ---- epilogue B: target top-k ----
  for (int tc = 0; tc < 8; ++tc) {
    if (mixs[(wv << 3) | tc] < 0.5f) {          // wave-uniform
      int vcH = (wv + 3) * 14 + (tc + 3);
      int vnH = lact ? ((wv + nr) * 14 + (tc + nc)) : vcH;
      int cbi = lact ? ((ri + nr) * 14 + (tc + nc)) : 0;
      float v = lact ? Csc[rt][ri * 8 + tc][cbi] : 0.f;

      uint4 pA = prb[vnH * 3 + 0], pB = prb[vnH * 3 + 1], pC = prb[vnH * 3 + 2];
      uint4 qA = prb[vcH * 3 + 0], qB = prb[vcH * 3 + 1], qC = prb[vcH * 3 + 2];
      float p0 = 0, p1 = 0, p2 = 0;
      p0 = fd(qA.x,pA.x,p0); p0 = fd(qA.y,pA.y,p0); p0 = fd(qA.z,pA.z,p0); p0 = fd(qA.w,pA.w,p0);
      p1 = fd(qB.x,pB.x,p1); p1 = fd(qB.y,pB.y,p1); p1 = fd(qB.z,pB.z,p1); p1 = fd(qB.w,pB.w,p1);
      p2 = fd(qC.x,pC.x,p2); p2 = fd(qC.y,pC.y,p2); p2 = fd(qC.z,pC.z,p2); p2 = fd(qC.w,pC.w,p2);
      float cp = (p0 + p1) + p2;                // OOB: staged 1/19 pattern -> 1/19

      // u32 sortable key: top-26 monotone float bits | lane (distinct)
      u32 bits = __float_as_uint(v);
      u32 mono = (bits & 0x80000000u) ? ~bits : (bits | 0x80000000u);
      u32 key = (mono & 0xFFFFFFC0u) | (u32)lane;
      ksh[wv][lane] = key;
      int rd = 0;
      const uint4* kr = (const uint4*)ksh[wv];
#pragma unroll
      for (int j = 0; j < 12; j++) {
        uint4 qq = kr[j];
        rd += (qq.x > key); rd += (qq.y > key); rd += (qq.z > key); rd += (qq.w > key);
      }
      rd += (ksh[wv][48] > key);
      if (lact) {
        if (rd < 9)   posa += v * cp;                     // top-9 most similar
        if (rd >= 41) nega += (1.f - v) * (1.f - cp);     // bottom-8 of 49
      }
      cntW += 1.f;
    }
  }

  // ---- reduce ----
#pragma unroll
  for (int off = 32; off; off >>= 1) {
    psum += __shfl_xor(psum, off); ssum += __shfl_xor(ssum, off);
    posa += __shfl_xor(posa, off); nega += __shfl_xor(nega, off);
  }
  if (lane == 0) {
    sacc[wv][0] = psum;  sacc[wv][1] = pcntW; sacc[wv][2] = ssum;
    sacc[wv][3] = posa;  sacc[wv][4] = nega;  sacc[wv][5] = vcntW;
    sacc[wv][6] = cntW;  sacc[wv][7] = 0.f;
  }
  __syncthreads();
  if (t < 8) {
    float s = 0.f;
#pragma unroll
    for (int k = 0; k < 8; k++) s += sacc[k][t];
    partials[(size_t)bid * 8 + t] = s;
  }
}

// ---------- F: reduce NTILE partials, combine ----------
__global__ __launch_bounds__(256) void finish_kernel(
    const float* __restrict__ partials, float* __restrict__ out) {
  int t = threadIdx.x, lane = t & 63, wv = t >> 6;
  float s0=0,s1=0,s2=0,s3=0,s4=0,s5=0,s6=0;
  for (int r = t; r < NTILE; r += 256) {
    const float4* p = (const float4*)(partials + (size_t)r * 8);
    float4 x = p[0], y = p[1];
    s0 += x.x; s1 += x.y; s2 += x.z; s3 += x.w;
    s4 += y.x; s5 += y.y; s6 += y.z;
  }
#pragma unroll
  for (int off = 32; off; off >>= 1) {
    s0 += __shfl_xor(s0, off); s1 += __shfl_xor(s1, off);
    s2 += __shfl_xor(s2, off); s3 += __shfl_xor(s3, off);
    s4 += __shfl_xor(s4, off); s5 += __shfl_xor(s5, off);
    s6 += __shfl_xor(s6, off);
  }
  __shared__ float sacc[4][8];
  if (lane == 0) {
    sacc[wv][0]=s0; sacc[wv][1]=s1; sacc[wv][2]=s2; sacc[wv][3]=s3;
    sacc[wv][4]=s4; sacc[wv][5]=s5; sacc[wv][6]=s6;
  }
  __syncthreads();
  if (t == 0) {
    float a[7];
#pragma unroll
    for (int c = 0; c < 7; c++) a[c] = sacc[0][c] + sacc[1][c] + sacc[2][c] + sacc[3][c];
    float psum = a[0], pcnt = a[1], ssum = a[2];
    float posa = a[3], nega = a[4], vcnt = a[5], cnt = a[6];
    float nsum = ssum - psum;
    float ncnt = 49.f * vcnt - pcnt;
    out[0] = -(psum / fmaxf(pcnt, 1.0f));
    out[1] =  (nsum / fmaxf(ncnt, 1.0f));
    out[2] = -(posa / fmaxf(9.0f * cnt, 1.0f));
    out[3] = -(nega / fmaxf(8.0f * cnt, 1.0f));
  }
}

extern "C" void kernel_launch(void* const* d_in, const int* in_sizes, int n_in,
                              void* d_out, int out_size, void* d_ws, size_t ws_size,
                              hipStream_t stream) {
  const float* logits = (const float*)d_in[0];
  const int*   gt     = (const int*)  d_in[1];
  const float* xema   = (const float*)d_in[2];
  const float* xsrc   = (const float*)d_in[3];
  const float* mix    = (const float*)d_in[4];
  float* out = (float*)d_out;

  float* partials = (float*)d_ws;                                 // NTILE*8 f32 = 16 KB
  u16* fsrc = (u16*)((char*)d_ws + NTILE * 8 * sizeof(float));    // NPIX*FSTR f16 = 4 MB
  u16* fema = fsrc + (size_t)NPIX * FSTR;                         // 4 MB
  u16* pt   = fema + (size_t)NPIX * FSTR;                         // NPIX*PSTR f16 = 1.5 MB

  pre_kernel<<<1152, 256, 0, stream>>>(logits, xsrc, xema, fsrc, fema, pt);
  st_kernel<<<NTILE, 512, 0, stream>>>(fsrc, fema, pt, gt, mix, partials);
  finish_kernel<<<1, 256, 0, stream>>>(partials, out);
}